// Round 5
// baseline (84.590 us; speedup 1.0000x reference)
//
#include <hip/hip_runtime.h>

#define NH 8
#define DCM 64
#define NB 2
#define NS 512
#define NL 384
#define LN_EPS 1e-5f
#define INV_SQRT_C 0.35355339059327379f

typedef __attribute__((ext_vector_type(8))) short short8v;   // 8 bf16 (4 VGPRs)
typedef __attribute__((ext_vector_type(4))) float f32x4;

__device__ __forceinline__ float4 ld4(const float* p) {
  return *reinterpret_cast<const float4*>(p);
}
__device__ __forceinline__ unsigned short f2bf(float f) {
  unsigned int b = __float_as_uint(f);
  b += 0x7FFFu + ((b >> 16) & 1u);          // round-to-nearest-even
  return (unsigned short)(b >> 16);
}
__device__ __forceinline__ float bf2f(unsigned short u) {
  return __uint_as_float(((unsigned int)u) << 16);
}

// ---------------------------------------------------------------------------
// Prep: wt[0..4095]=wg^T bf16 [n][k]; wt[4096..8191]=wo^T; wt[8192..12287]=wv^T.
// ---------------------------------------------------------------------------
__global__ void prep_weights(const float* __restrict__ wg,
                             const float* __restrict__ wo,
                             const float* __restrict__ wv,
                             unsigned short* __restrict__ wt) {
  int i = blockIdx.x * 256 + threadIdx.x;
  if (i < 4096) {
    int n = i >> 6, k = i & 63;
    wt[i]        = f2bf(wg[k * DCM + n]);
    wt[4096 + i] = f2bf(wo[k * DCM + n]);
    wt[8192 + i] = f2bf(wv[k * DCM + n]);
  }
}

// ---------------------------------------------------------------------------
// Fused, 512 threads (8 waves) per WG, one WG per (b,l) column.
//   P1: stream+LN (depth-4 prefetch) -> x bf16 LDS (swizzled) + masked sum -> qk
//   P2: merged: logits MFMA -> p (via P_T, same wave) ; V MFMA ; og += p*V
//   P3: gating MFMA -> transpose IN-PLACE into dead x_lds tile -> output MFMA
// LDS = 64K(x) + 1K(mask) + 10.5K(scratch) + 2K(qk) = 77.8 KB -> 2 WGs/CU,
// 16 waves/CU (4/SIMD).
// ---------------------------------------------------------------------------
__global__ __launch_bounds__(512, 4) void fused(
    const float* __restrict__ m, const float* __restrict__ msk,
    const float* __restrict__ lnw, const float* __restrict__ lnb,
    const float* __restrict__ wq, const float* __restrict__ wk,
    const unsigned short* __restrict__ wt,
    const float* __restrict__ bg, const float* __restrict__ bo,
    float* __restrict__ out)
{
  const int col = blockIdx.x;              // b*NL + l
  const int b = col / NL, l = col % NL;
  const int tid = threadIdx.x;
  const int wave = tid >> 6, lane = tid & 63;   // wave 0..7

  __shared__ __align__(16) unsigned short x_lds[NS * DCM];   // 64 KB, swizzled
  __shared__ __align__(16) unsigned short mask_s[NS];        // 1 KB (0/1 exact)
  __shared__ __align__(16) unsigned char scratch[10752];     // overlays below
  __shared__ __align__(16) unsigned short qk_bf[16 * DCM];   // 2 KB, rows 8-15 = 0

  float* redf  = (float*)scratch;                   // [8][64] floats 0..511
  float* dredf = redf + 512;                        // 8
  float* qinf  = redf + 528;                        // 64 (16B aligned)
  float* qsf   = redf + 592;                        // 64
  unsigned short* P_T = (unsigned short*)scratch;   // [8][512] bf16, 8 KB (P2)
  float* ogredf = (float*)(scratch + 8192);         // [8][64]
  float* smredf = (float*)(scratch + 10240);        // [8][8]
  float* ogsf   = (float*)(scratch + 10496);        // [64]

  for (int i = tid; i < NS; i += 512)
    mask_s[i] = f2bf(msk[(b * NS + i) * NL + l]);

  // ---------------- Phase 1: stream m once, LN, x->LDS bf16, masked sum ----
  const int c8 = lane & 7;          // channel block: cm = c8*8 .. c8*8+7
  const int r8 = lane >> 3;         // row within 8-row group
  float lw8[8], lb8[8];
#pragma unroll
  for (int k = 0; k < 8; ++k) { lw8[k] = lnw[c8 * 8 + k]; lb8[k] = lnb[c8 * 8 + k]; }
  __syncthreads();                  // mask_s ready (read inside P1 loop)

  float qacc[8] = {0.f,0.f,0.f,0.f,0.f,0.f,0.f,0.f};
  float dacc = 0.f;
  const int rowbase = wave * 64;    // 64 rows per wave
  {
    const size_t rstep = (size_t)8 * NL * DCM;
    const float* mb = m + ((size_t)b * NS * NL + l) * DCM + c8 * 8
                    + (size_t)(rowbase + r8) * NL * DCM;
    auto process = [&](const float4& A, const float4& Bv, int s) {
      float xv[8] = {A.x, A.y, A.z, A.w, Bv.x, Bv.y, Bv.z, Bv.w};
      float s1 = 0.f, s2 = 0.f;
#pragma unroll
      for (int k = 0; k < 8; ++k) { s1 += xv[k]; s2 += xv[k] * xv[k]; }
#pragma unroll
      for (int o = 1; o <= 4; o <<= 1) { s1 += __shfl_xor(s1, o); s2 += __shfl_xor(s2, o); }
      const float mu = s1 * 0.015625f;
      const float rs = rsqrtf(s2 * 0.015625f - mu * mu + LN_EPS);
      const float mk = bf2f(mask_s[s]);
      short8v xp;
#pragma unroll
      for (int k = 0; k < 8; ++k) {
        float xn = (xv[k] - mu) * rs * lw8[k] + lb8[k];
        xp[k] = (short)f2bf(xn);
        qacc[k] += xn * mk;
      }
      dacc += mk;
      *reinterpret_cast<short8v*>(&x_lds[s * DCM + ((c8 * 8) ^ ((s & 7) << 3))]) = xp;
    };
    // 8 iterations, depth-4 prefetch, static register indexing
    float4 f0a = ld4(mb),             f0b = ld4(mb + 4);
    float4 f1a = ld4(mb + rstep),     f1b = ld4(mb + rstep + 4);
    float4 f2a = ld4(mb + 2 * rstep), f2b = ld4(mb + 2 * rstep + 4);
    float4 f3a = ld4(mb + 3 * rstep), f3b = ld4(mb + 3 * rstep + 4);
#pragma unroll
    for (int blk = 0; blk < 2; ++blk) {
      const int it0 = blk * 4;
      process(f0a, f0b, rowbase + (it0 + 0) * 8 + r8);
      if (blk < 1) { f0a = ld4(mb + (size_t)(it0 + 4) * rstep);
                     f0b = ld4(mb + (size_t)(it0 + 4) * rstep + 4); }
      process(f1a, f1b, rowbase + (it0 + 1) * 8 + r8);
      if (blk < 1) { f1a = ld4(mb + (size_t)(it0 + 5) * rstep);
                     f1b = ld4(mb + (size_t)(it0 + 5) * rstep + 4); }
      process(f2a, f2b, rowbase + (it0 + 2) * 8 + r8);
      if (blk < 1) { f2a = ld4(mb + (size_t)(it0 + 6) * rstep);
                     f2b = ld4(mb + (size_t)(it0 + 6) * rstep + 4); }
      process(f3a, f3b, rowbase + (it0 + 3) * 8 + r8);
      if (blk < 1) { f3a = ld4(mb + (size_t)(it0 + 7) * rstep);
                     f3b = ld4(mb + (size_t)(it0 + 7) * rstep + 4); }
    }
  }
#pragma unroll
  for (int o = 8; o <= 32; o <<= 1) {
#pragma unroll
    for (int k = 0; k < 8; ++k) qacc[k] += __shfl_xor(qacc[k], o);
    dacc += __shfl_xor(dacc, o);
  }
  if (lane < 8) {
    float4 t0; t0.x = qacc[0]; t0.y = qacc[1]; t0.z = qacc[2]; t0.w = qacc[3];
    float4 t1; t1.x = qacc[4]; t1.y = qacc[5]; t1.z = qacc[6]; t1.w = qacc[7];
    *reinterpret_cast<float4*>(&redf[wave * DCM + lane * 8])     = t0;
    *reinterpret_cast<float4*>(&redf[wave * DCM + lane * 8 + 4]) = t1;
  }
  // xor-reduce over {8,16,32} sums r8 only -> each of the wave's 64 rows
  // counted exactly once (c8 replicas in lane bits 0-2 never merged)
  if (lane == 0) dredf[wave] = dacc;
  __syncthreads();

  if (tid < DCM) {
    float dn = 0.f, a = 0.f;
#pragma unroll
    for (int w = 0; w < 8; ++w) { dn += dredf[w]; a += redf[w * DCM + tid]; }
    qinf[tid] = a / fmaxf(dn, 1.0f);
  }
  __syncthreads();
  if (tid < DCM) {
    float a = 0.f;
    for (int j = 0; j < DCM; ++j) a += qinf[j] * wq[j * DCM + tid];
    qsf[tid] = a;
  }
  __syncthreads();
  // qk_bf[h][cm] = (sum_c q[h*8+c]*wk[cm][h*8+c]) / sqrt(C), bf16; h>=8 -> 0
  for (int idx = tid; idx < 16 * DCM; idx += 512) {
    int h = idx >> 6, cm = idx & 63;
    float a = 0.f;
    if (h < NH) {
#pragma unroll
      for (int c = 0; c < 8; ++c) a += qsf[h * 8 + c] * wk[cm * DCM + h * 8 + c];
      a *= INV_SQRT_C;
    }
    qk_bf[idx] = f2bf(a);
  }
  __syncthreads();   // q-chain scratch dead; scratch becomes P_T

  // ---------------- Phase 2 (merged): logits+p, V, og += p*V ---------------
  const int bcol = lane & 15;
  const int kg = lane >> 4;
  short8v qkB0 = *reinterpret_cast<const short8v*>(&qk_bf[bcol * DCM + kg * 8]);
  short8v qkB1 = *reinterpret_cast<const short8v*>(&qk_bf[bcol * DCM + 32 + kg * 8]);
  short8v wvB[4][2];
#pragma unroll
  for (int nt = 0; nt < 4; ++nt)
#pragma unroll
    for (int kw = 0; kw < 2; ++kw)
      wvB[nt][kw] = *reinterpret_cast<const short8v*>(
          &wt[8192 + (nt * 16 + bcol) * DCM + kw * 32 + kg * 8]);
  float smacc = 0.f;
  float ogacc[4] = {0.f, 0.f, 0.f, 0.f};
  for (int t = 0; t < 4; ++t) {
    const int tilebase = rowbase + t * 16;
    const int arow = tilebase + bcol;
    const int swz = (arow & 7) << 3;
    short8v a0 = *reinterpret_cast<const short8v*>(&x_lds[arow * DCM + ((kg * 8) ^ swz)]);
    short8v a1 = *reinterpret_cast<const short8v*>(&x_lds[arow * DCM + ((32 + kg * 8) ^ swz)]);
    f32x4 L = (f32x4){0.f, 0.f, 0.f, 0.f};
    L = __builtin_amdgcn_mfma_f32_16x16x32_bf16(a0, qkB0, L, 0, 0, 0);
    L = __builtin_amdgcn_mfma_f32_16x16x32_bf16(a1, qkB1, L, 0, 0, 0);
    const int s0 = tilebase + kg * 4;                // C rows = kg*4+r
    short4 mk4 = *reinterpret_cast<const short4*>(&mask_s[s0]);
    // logits are tiny (global query is a mean) -> exp without max-sub safe
    float p0 = bf2f((unsigned short)mk4.x) * __expf(L[0]);
    float p1 = bf2f((unsigned short)mk4.y) * __expf(L[1]);
    float p2 = bf2f((unsigned short)mk4.z) * __expf(L[2]);
    float p3 = bf2f((unsigned short)mk4.w) * __expf(L[3]);
    smacc += (p0 + p1) + (p2 + p3);
    if (bcol < NH) {                                 // producer lanes
      short4 pw;
      pw.x = (short)f2bf(p0); pw.y = (short)f2bf(p1);
      pw.z = (short)f2bf(p2); pw.w = (short)f2bf(p3);
      *reinterpret_cast<short4*>(&P_T[bcol * NS + (s0 ^ (bcol << 3))]) = pw;
    }
    f32x4 V[4];
#pragma unroll
    for (int nt = 0; nt < 4; ++nt) {
      V[nt] = (f32x4){0.f, 0.f, 0.f, 0.f};
      V[nt] = __builtin_amdgcn_mfma_f32_16x16x32_bf16(a0, wvB[nt][0], V[nt], 0, 0, 0);
      V[nt] = __builtin_amdgcn_mfma_f32_16x16x32_bf16(a1, wvB[nt][1], V[nt], 0, 0, 0);
    }
    // consume p (stored above by this same wave; in-wave LDS ops are ordered)
#pragma unroll
    for (int nt = 0; nt < 4; ++nt) {
      const int h2 = 2 * nt + (bcol >> 3);           // head of this lane's col
      short4 p4 = *reinterpret_cast<const short4*>(&P_T[h2 * NS + (s0 ^ (h2 << 3))]);
      ogacc[nt] += bf2f((unsigned short)p4.x) * V[nt][0]
                 + bf2f((unsigned short)p4.y) * V[nt][1]
                 + bf2f((unsigned short)p4.z) * V[nt][2]
                 + bf2f((unsigned short)p4.w) * V[nt][3];
    }
  }
  smacc += __shfl_xor(smacc, 16); smacc += __shfl_xor(smacc, 32);
  if (lane < NH) smredf[wave * NH + lane] = smacc;
#pragma unroll
  for (int nt = 0; nt < 4; ++nt) {
    ogacc[nt] += __shfl_xor(ogacc[nt], 16);
    ogacc[nt] += __shfl_xor(ogacc[nt], 32);
  }
  if (lane < 16) {
#pragma unroll
    for (int nt = 0; nt < 4; ++nt) ogredf[wave * DCM + nt * 16 + lane] = ogacc[nt];
  }
  __syncthreads();
  if (tid < DCM) {
    float smT = 0.f, a = 0.f;
#pragma unroll
    for (int w = 0; w < 8; ++w) {
      smT += smredf[w * NH + (tid >> 3)];
      a += ogredf[w * DCM + tid];
    }
    ogsf[tid] = a / fmaxf(smT, 1e-30f);
  }
  __syncthreads();   // og ready

  // ---------------- Phase 3: gating MFMA -> in-place transpose -> out ------
  short8v wgB[4][2], woB[4][2];
  float bgv[4], bov[4], ogv[4];
#pragma unroll
  for (int nt = 0; nt < 4; ++nt) {
    const int ncol = nt * 16 + bcol;
#pragma unroll
    for (int kw = 0; kw < 2; ++kw) {
      wgB[nt][kw] = *reinterpret_cast<const short8v*>(&wt[ncol * DCM + kw * 32 + kg * 8]);
      woB[nt][kw] = *reinterpret_cast<const short8v*>(&wt[4096 + ncol * DCM + kw * 32 + kg * 8]);
    }
    bgv[nt] = bg[ncol]; bov[nt] = bo[ncol]; ogv[nt] = ogsf[ncol];
  }
  const size_t outbase = ((size_t)b * NS * NL + l) * DCM;

  for (int t = 0; t < 4; ++t) {
    const int tilebase = rowbase + t * 16;
    const int arow = tilebase + bcol;
    const int swz = (arow & 7) << 3;
    short8v a0 = *reinterpret_cast<const short8v*>(&x_lds[arow * DCM + ((kg * 8) ^ swz)]);
    short8v a1 = *reinterpret_cast<const short8v*>(&x_lds[arow * DCM + ((32 + kg * 8) ^ swz)]);
    f32x4 accG[4];
#pragma unroll
    for (int nt = 0; nt < 4; ++nt) {
      accG[nt] = (f32x4){0.f, 0.f, 0.f, 0.f};
      accG[nt] = __builtin_amdgcn_mfma_f32_16x16x32_bf16(a0, wgB[nt][0], accG[nt], 0, 0, 0);
      accG[nt] = __builtin_amdgcn_mfma_f32_16x16x32_bf16(a1, wgB[nt][1], accG[nt], 0, 0, 0);
    }
    // gate*og, transposed bf16 written IN-PLACE into this (now dead) x tile.
    // In-wave LDS ordering: the a0/a1 reads above complete before these
    // writes; each wave owns its rows exclusively.
#pragma unroll
    for (int nt = 0; nt < 4; ++nt) {
      const int cc = nt * 16 + bcol;
#pragma unroll
      for (int r = 0; r < 4; ++r) {
        const int r2 = kg * 4 + r;                 // C-layout row within tile
        float gx = accG[nt][r] + bgv[nt];
        float g = 1.0f / (1.0f + __expf(-gx));
        x_lds[(tilebase + r2) * DCM + (cc ^ ((r2 & 7) << 3))] = f2bf(g * ogv[nt]);
      }
    }
    short8v b0 = *reinterpret_cast<const short8v*>(
        &x_lds[(tilebase + bcol) * DCM + ((kg * 8) ^ ((bcol & 7) << 3))]);
    short8v b1 = *reinterpret_cast<const short8v*>(
        &x_lds[(tilebase + bcol) * DCM + ((32 + kg * 8) ^ ((bcol & 7) << 3))]);
    f32x4 accO[4];
#pragma unroll
    for (int nt = 0; nt < 4; ++nt) {
      accO[nt] = (f32x4){0.f, 0.f, 0.f, 0.f};
      accO[nt] = __builtin_amdgcn_mfma_f32_16x16x32_bf16(b0, woB[nt][0], accO[nt], 0, 0, 0);
      accO[nt] = __builtin_amdgcn_mfma_f32_16x16x32_bf16(b1, woB[nt][1], accO[nt], 0, 0, 0);
    }
#pragma unroll
    for (int nt = 0; nt < 4; ++nt) {
#pragma unroll
      for (int r = 0; r < 4; ++r) {
        const int orow = tilebase + kg * 4 + r;
        const float mk = bf2f(mask_s[orow]);
        out[outbase + (size_t)orow * NL * DCM + nt * 16 + bcol] = (accO[nt][r] + bov[nt]) * mk;
      }
    }
  }
}

extern "C" void kernel_launch(void* const* d_in, const int* in_sizes, int n_in,
                              void* d_out, int out_size, void* d_ws, size_t ws_size,
                              hipStream_t stream) {
  (void)in_sizes; (void)n_in; (void)out_size; (void)ws_size;
  const float* m   = (const float*)d_in[0];
  const float* msk = (const float*)d_in[1];
  const float* lnw = (const float*)d_in[2];
  const float* lnb = (const float*)d_in[3];
  const float* wq  = (const float*)d_in[4];
  const float* wk  = (const float*)d_in[5];
  const float* wv  = (const float*)d_in[6];
  const float* wg  = (const float*)d_in[7];
  const float* bg  = (const float*)d_in[8];
  const float* wo  = (const float*)d_in[9];
  const float* bo  = (const float*)d_in[10];
  unsigned short* wt = (unsigned short*)d_ws;   // 12288 bf16 = 24 KB scratch
  float* out = (float*)d_out;

  prep_weights<<<dim3(16), dim3(256), 0, stream>>>(wg, wo, wv, wt);
  fused<<<dim3(NB * NL), dim3(512), 0, stream>>>(
      m, msk, lnw, lnb, wq, wk, wt, bg, bo, out);
}

// Round 6
// 79.768 us; speedup vs baseline: 1.0604x; 1.0604x over previous
//
#include <hip/hip_runtime.h>

#define NH 8
#define DCM 64
#define NB 2
#define NS 512
#define NL 384
#define LN_EPS 1e-5f
#define INV_SQRT_C 0.35355339059327379f

typedef __attribute__((ext_vector_type(8))) short short8v;   // 8 bf16 (4 VGPRs)
typedef __attribute__((ext_vector_type(4))) float f32x4;

__device__ __forceinline__ float4 ld4(const float* p) {
  return *reinterpret_cast<const float4*>(p);
}
__device__ __forceinline__ unsigned short f2bf(float f) {
  unsigned int b = __float_as_uint(f);
  b += 0x7FFFu + ((b >> 16) & 1u);          // round-to-nearest-even
  return (unsigned short)(b >> 16);
}
__device__ __forceinline__ float bf2f(unsigned short u) {
  return __uint_as_float(((unsigned int)u) << 16);
}

// ---------------------------------------------------------------------------
// Prep: wt[0..4095]=wg^T bf16 [n][k]; wt[4096..8191]=wo^T; wt[8192..12287]=wv^T.
// ---------------------------------------------------------------------------
__global__ void prep_weights(const float* __restrict__ wg,
                             const float* __restrict__ wo,
                             const float* __restrict__ wv,
                             unsigned short* __restrict__ wt) {
  int i = blockIdx.x * 256 + threadIdx.x;
  if (i < 4096) {
    int n = i >> 6, k = i & 63;
    wt[i]        = f2bf(wg[k * DCM + n]);
    wt[4096 + i] = f2bf(wo[k * DCM + n]);
    wt[8192 + i] = f2bf(wv[k * DCM + n]);
  }
}

// ---------------------------------------------------------------------------
// Fused, 512 threads (8 waves) per WG, one WG per (b,l) column.
//   P1: stream+LN (depth-4 prefetch) -> x bf16 LDS (swizzled) + masked sum -> qk
//   P2: merged: logits MFMA -> p (via P_T, same wave) ; V MFMA ; og += p*V
//   P3: gating MFMA -> transpose IN-PLACE into dead x_lds tile -> output MFMA
// LDS = 77.8 KB -> 2 WGs/CU, 16 waves/CU (4/SIMD).
// __launch_bounds__(512, 2): R5 measured that arg2=4 at 512 threads caps VGPR
// at 64 (compiler treats it as 4 blocks/CU = 8 waves/SIMD) -> massive spills
// (+77 MB HBM). arg2=2 => 2 blocks/CU = 4 waves/SIMD => 128-VGPR cap; natural
// usage ~112 fits spill-free at the same occupancy LDS allows anyway.
// ---------------------------------------------------------------------------
__global__ __launch_bounds__(512, 2) void fused(
    const float* __restrict__ m, const float* __restrict__ msk,
    const float* __restrict__ lnw, const float* __restrict__ lnb,
    const float* __restrict__ wq, const float* __restrict__ wk,
    const unsigned short* __restrict__ wt,
    const float* __restrict__ bg, const float* __restrict__ bo,
    float* __restrict__ out)
{
  const int col = blockIdx.x;              // b*NL + l
  const int b = col / NL, l = col % NL;
  const int tid = threadIdx.x;
  const int wave = tid >> 6, lane = tid & 63;   // wave 0..7

  __shared__ __align__(16) unsigned short x_lds[NS * DCM];   // 64 KB, swizzled
  __shared__ __align__(16) unsigned short mask_s[NS];        // 1 KB (0/1 exact)
  __shared__ __align__(16) unsigned char scratch[10752];     // overlays below
  __shared__ __align__(16) unsigned short qk_bf[16 * DCM];   // 2 KB, rows 8-15 = 0

  float* redf  = (float*)scratch;                   // [8][64] floats 0..511
  float* dredf = redf + 512;                        // 8
  float* qinf  = redf + 528;                        // 64 (16B aligned)
  float* qsf   = redf + 592;                        // 64
  unsigned short* P_T = (unsigned short*)scratch;   // [8][512] bf16, 8 KB (P2)
  float* ogredf = (float*)(scratch + 8192);         // [8][64]
  float* smredf = (float*)(scratch + 10240);        // [8][8]
  float* ogsf   = (float*)(scratch + 10496);        // [64]

  for (int i = tid; i < NS; i += 512)
    mask_s[i] = f2bf(msk[(b * NS + i) * NL + l]);

  // ---------------- Phase 1: stream m once, LN, x->LDS bf16, masked sum ----
  const int c8 = lane & 7;          // channel block: cm = c8*8 .. c8*8+7
  const int r8 = lane >> 3;         // row within 8-row group
  float lw8[8], lb8[8];
#pragma unroll
  for (int k = 0; k < 8; ++k) { lw8[k] = lnw[c8 * 8 + k]; lb8[k] = lnb[c8 * 8 + k]; }
  __syncthreads();                  // mask_s ready (read inside P1 loop)

  float qacc[8] = {0.f,0.f,0.f,0.f,0.f,0.f,0.f,0.f};
  float dacc = 0.f;
  const int rowbase = wave * 64;    // 64 rows per wave
  {
    const size_t rstep = (size_t)8 * NL * DCM;
    const float* mb = m + ((size_t)b * NS * NL + l) * DCM + c8 * 8
                    + (size_t)(rowbase + r8) * NL * DCM;
    auto process = [&](const float4& A, const float4& Bv, int s) {
      float xv[8] = {A.x, A.y, A.z, A.w, Bv.x, Bv.y, Bv.z, Bv.w};
      float s1 = 0.f, s2 = 0.f;
#pragma unroll
      for (int k = 0; k < 8; ++k) { s1 += xv[k]; s2 += xv[k] * xv[k]; }
#pragma unroll
      for (int o = 1; o <= 4; o <<= 1) { s1 += __shfl_xor(s1, o); s2 += __shfl_xor(s2, o); }
      const float mu = s1 * 0.015625f;
      const float rs = rsqrtf(s2 * 0.015625f - mu * mu + LN_EPS);
      const float mk = bf2f(mask_s[s]);
      short8v xp;
#pragma unroll
      for (int k = 0; k < 8; ++k) {
        float xn = (xv[k] - mu) * rs * lw8[k] + lb8[k];
        xp[k] = (short)f2bf(xn);
        qacc[k] += xn * mk;
      }
      dacc += mk;
      *reinterpret_cast<short8v*>(&x_lds[s * DCM + ((c8 * 8) ^ ((s & 7) << 3))]) = xp;
    };
    // 8 iterations, depth-4 prefetch, static register indexing
    float4 f0a = ld4(mb),             f0b = ld4(mb + 4);
    float4 f1a = ld4(mb + rstep),     f1b = ld4(mb + rstep + 4);
    float4 f2a = ld4(mb + 2 * rstep), f2b = ld4(mb + 2 * rstep + 4);
    float4 f3a = ld4(mb + 3 * rstep), f3b = ld4(mb + 3 * rstep + 4);
#pragma unroll
    for (int blk = 0; blk < 2; ++blk) {
      const int it0 = blk * 4;
      process(f0a, f0b, rowbase + (it0 + 0) * 8 + r8);
      if (blk < 1) { f0a = ld4(mb + (size_t)(it0 + 4) * rstep);
                     f0b = ld4(mb + (size_t)(it0 + 4) * rstep + 4); }
      process(f1a, f1b, rowbase + (it0 + 1) * 8 + r8);
      if (blk < 1) { f1a = ld4(mb + (size_t)(it0 + 5) * rstep);
                     f1b = ld4(mb + (size_t)(it0 + 5) * rstep + 4); }
      process(f2a, f2b, rowbase + (it0 + 2) * 8 + r8);
      if (blk < 1) { f2a = ld4(mb + (size_t)(it0 + 6) * rstep);
                     f2b = ld4(mb + (size_t)(it0 + 6) * rstep + 4); }
      process(f3a, f3b, rowbase + (it0 + 3) * 8 + r8);
      if (blk < 1) { f3a = ld4(mb + (size_t)(it0 + 7) * rstep);
                     f3b = ld4(mb + (size_t)(it0 + 7) * rstep + 4); }
    }
  }
#pragma unroll
  for (int o = 8; o <= 32; o <<= 1) {
#pragma unroll
    for (int k = 0; k < 8; ++k) qacc[k] += __shfl_xor(qacc[k], o);
    dacc += __shfl_xor(dacc, o);
  }
  if (lane < 8) {
    float4 t0; t0.x = qacc[0]; t0.y = qacc[1]; t0.z = qacc[2]; t0.w = qacc[3];
    float4 t1; t1.x = qacc[4]; t1.y = qacc[5]; t1.z = qacc[6]; t1.w = qacc[7];
    *reinterpret_cast<float4*>(&redf[wave * DCM + lane * 8])     = t0;
    *reinterpret_cast<float4*>(&redf[wave * DCM + lane * 8 + 4]) = t1;
  }
  // xor-reduce over {8,16,32} sums r8 only -> each of the wave's 64 rows
  // counted exactly once (c8 replicas in lane bits 0-2 never merged)
  if (lane == 0) dredf[wave] = dacc;
  __syncthreads();

  if (tid < DCM) {
    float dn = 0.f, a = 0.f;
#pragma unroll
    for (int w = 0; w < 8; ++w) { dn += dredf[w]; a += redf[w * DCM + tid]; }
    qinf[tid] = a / fmaxf(dn, 1.0f);
  }
  __syncthreads();
  if (tid < DCM) {
    float a = 0.f;
    for (int j = 0; j < DCM; ++j) a += qinf[j] * wq[j * DCM + tid];
    qsf[tid] = a;
  }
  __syncthreads();
  // qk_bf[h][cm] = (sum_c q[h*8+c]*wk[cm][h*8+c]) / sqrt(C), bf16; h>=8 -> 0
  for (int idx = tid; idx < 16 * DCM; idx += 512) {
    int h = idx >> 6, cm = idx & 63;
    float a = 0.f;
    if (h < NH) {
#pragma unroll
      for (int c = 0; c < 8; ++c) a += qsf[h * 8 + c] * wk[cm * DCM + h * 8 + c];
      a *= INV_SQRT_C;
    }
    qk_bf[idx] = f2bf(a);
  }
  __syncthreads();   // q-chain scratch dead; scratch becomes P_T

  // ---------------- Phase 2 (merged): logits+p, V, og += p*V ---------------
  const int bcol = lane & 15;
  const int kg = lane >> 4;
  short8v qkB0 = *reinterpret_cast<const short8v*>(&qk_bf[bcol * DCM + kg * 8]);
  short8v qkB1 = *reinterpret_cast<const short8v*>(&qk_bf[bcol * DCM + 32 + kg * 8]);
  short8v wvB[4][2];
#pragma unroll
  for (int nt = 0; nt < 4; ++nt)
#pragma unroll
    for (int kw = 0; kw < 2; ++kw)
      wvB[nt][kw] = *reinterpret_cast<const short8v*>(
          &wt[8192 + (nt * 16 + bcol) * DCM + kw * 32 + kg * 8]);
  float smacc = 0.f;
  float ogacc[4] = {0.f, 0.f, 0.f, 0.f};
  for (int t = 0; t < 4; ++t) {
    const int tilebase = rowbase + t * 16;
    const int arow = tilebase + bcol;
    const int swz = (arow & 7) << 3;
    short8v a0 = *reinterpret_cast<const short8v*>(&x_lds[arow * DCM + ((kg * 8) ^ swz)]);
    short8v a1 = *reinterpret_cast<const short8v*>(&x_lds[arow * DCM + ((32 + kg * 8) ^ swz)]);
    f32x4 L = (f32x4){0.f, 0.f, 0.f, 0.f};
    L = __builtin_amdgcn_mfma_f32_16x16x32_bf16(a0, qkB0, L, 0, 0, 0);
    L = __builtin_amdgcn_mfma_f32_16x16x32_bf16(a1, qkB1, L, 0, 0, 0);
    const int s0 = tilebase + kg * 4;                // C rows = kg*4+r
    short4 mk4 = *reinterpret_cast<const short4*>(&mask_s[s0]);
    // logits are tiny (global query is a mean) -> exp without max-sub safe
    float p0 = bf2f((unsigned short)mk4.x) * __expf(L[0]);
    float p1 = bf2f((unsigned short)mk4.y) * __expf(L[1]);
    float p2 = bf2f((unsigned short)mk4.z) * __expf(L[2]);
    float p3 = bf2f((unsigned short)mk4.w) * __expf(L[3]);
    smacc += (p0 + p1) + (p2 + p3);
    if (bcol < NH) {                                 // producer lanes
      short4 pw;
      pw.x = (short)f2bf(p0); pw.y = (short)f2bf(p1);
      pw.z = (short)f2bf(p2); pw.w = (short)f2bf(p3);
      *reinterpret_cast<short4*>(&P_T[bcol * NS + (s0 ^ (bcol << 3))]) = pw;
    }
    f32x4 V[4];
#pragma unroll
    for (int nt = 0; nt < 4; ++nt) {
      V[nt] = (f32x4){0.f, 0.f, 0.f, 0.f};
      V[nt] = __builtin_amdgcn_mfma_f32_16x16x32_bf16(a0, wvB[nt][0], V[nt], 0, 0, 0);
      V[nt] = __builtin_amdgcn_mfma_f32_16x16x32_bf16(a1, wvB[nt][1], V[nt], 0, 0, 0);
    }
    // consume p (stored above by this same wave; in-wave LDS ops are ordered)
#pragma unroll
    for (int nt = 0; nt < 4; ++nt) {
      const int h2 = 2 * nt + (bcol >> 3);           // head of this lane's col
      short4 p4 = *reinterpret_cast<const short4*>(&P_T[h2 * NS + (s0 ^ (h2 << 3))]);
      ogacc[nt] += bf2f((unsigned short)p4.x) * V[nt][0]
                 + bf2f((unsigned short)p4.y) * V[nt][1]
                 + bf2f((unsigned short)p4.z) * V[nt][2]
                 + bf2f((unsigned short)p4.w) * V[nt][3];
    }
  }
  smacc += __shfl_xor(smacc, 16); smacc += __shfl_xor(smacc, 32);
  if (lane < NH) smredf[wave * NH + lane] = smacc;
#pragma unroll
  for (int nt = 0; nt < 4; ++nt) {
    ogacc[nt] += __shfl_xor(ogacc[nt], 16);
    ogacc[nt] += __shfl_xor(ogacc[nt], 32);
  }
  if (lane < 16) {
#pragma unroll
    for (int nt = 0; nt < 4; ++nt) ogredf[wave * DCM + nt * 16 + lane] = ogacc[nt];
  }
  __syncthreads();
  if (tid < DCM) {
    float smT = 0.f, a = 0.f;
#pragma unroll
    for (int w = 0; w < 8; ++w) {
      smT += smredf[w * NH + (tid >> 3)];
      a += ogredf[w * DCM + tid];
    }
    ogsf[tid] = a / fmaxf(smT, 1e-30f);
  }
  __syncthreads();   // og ready

  // ---------------- Phase 3: gating MFMA -> in-place transpose -> out ------
  short8v wgB[4][2], woB[4][2];
  float bgv[4], bov[4], ogv[4];
#pragma unroll
  for (int nt = 0; nt < 4; ++nt) {
    const int ncol = nt * 16 + bcol;
#pragma unroll
    for (int kw = 0; kw < 2; ++kw) {
      wgB[nt][kw] = *reinterpret_cast<const short8v*>(&wt[ncol * DCM + kw * 32 + kg * 8]);
      woB[nt][kw] = *reinterpret_cast<const short8v*>(&wt[4096 + ncol * DCM + kw * 32 + kg * 8]);
    }
    bgv[nt] = bg[ncol]; bov[nt] = bo[ncol]; ogv[nt] = ogsf[ncol];
  }
  const size_t outbase = ((size_t)b * NS * NL + l) * DCM;

  for (int t = 0; t < 4; ++t) {
    const int tilebase = rowbase + t * 16;
    const int arow = tilebase + bcol;
    const int swz = (arow & 7) << 3;
    short8v a0 = *reinterpret_cast<const short8v*>(&x_lds[arow * DCM + ((kg * 8) ^ swz)]);
    short8v a1 = *reinterpret_cast<const short8v*>(&x_lds[arow * DCM + ((32 + kg * 8) ^ swz)]);
    f32x4 accG[4];
#pragma unroll
    for (int nt = 0; nt < 4; ++nt) {
      accG[nt] = (f32x4){0.f, 0.f, 0.f, 0.f};
      accG[nt] = __builtin_amdgcn_mfma_f32_16x16x32_bf16(a0, wgB[nt][0], accG[nt], 0, 0, 0);
      accG[nt] = __builtin_amdgcn_mfma_f32_16x16x32_bf16(a1, wgB[nt][1], accG[nt], 0, 0, 0);
    }
    // gate*og, transposed bf16 written IN-PLACE into this (now dead) x tile.
    // In-wave LDS ordering: the a0/a1 reads above complete before these
    // writes; each wave owns its rows exclusively.
#pragma unroll
    for (int nt = 0; nt < 4; ++nt) {
      const int cc = nt * 16 + bcol;
#pragma unroll
      for (int r = 0; r < 4; ++r) {
        const int r2 = kg * 4 + r;                 // C-layout row within tile
        float gx = accG[nt][r] + bgv[nt];
        float g = 1.0f / (1.0f + __expf(-gx));
        x_lds[(tilebase + r2) * DCM + (cc ^ ((r2 & 7) << 3))] = f2bf(g * ogv[nt]);
      }
    }
    short8v b0 = *reinterpret_cast<const short8v*>(
        &x_lds[(tilebase + bcol) * DCM + ((kg * 8) ^ ((bcol & 7) << 3))]);
    short8v b1 = *reinterpret_cast<const short8v*>(
        &x_lds[(tilebase + bcol) * DCM + ((32 + kg * 8) ^ ((bcol & 7) << 3))]);
    f32x4 accO[4];
#pragma unroll
    for (int nt = 0; nt < 4; ++nt) {
      accO[nt] = (f32x4){0.f, 0.f, 0.f, 0.f};
      accO[nt] = __builtin_amdgcn_mfma_f32_16x16x32_bf16(b0, woB[nt][0], accO[nt], 0, 0, 0);
      accO[nt] = __builtin_amdgcn_mfma_f32_16x16x32_bf16(b1, woB[nt][1], accO[nt], 0, 0, 0);
    }
#pragma unroll
    for (int nt = 0; nt < 4; ++nt) {
#pragma unroll
      for (int r = 0; r < 4; ++r) {
        const int orow = tilebase + kg * 4 + r;
        const float mk = bf2f(mask_s[orow]);
        out[outbase + (size_t)orow * NL * DCM + nt * 16 + bcol] = (accO[nt][r] + bov[nt]) * mk;
      }
    }
  }
}

extern "C" void kernel_launch(void* const* d_in, const int* in_sizes, int n_in,
                              void* d_out, int out_size, void* d_ws, size_t ws_size,
                              hipStream_t stream) {
  (void)in_sizes; (void)n_in; (void)out_size; (void)ws_size;
  const float* m   = (const float*)d_in[0];
  const float* msk = (const float*)d_in[1];
  const float* lnw = (const float*)d_in[2];
  const float* lnb = (const float*)d_in[3];
  const float* wq  = (const float*)d_in[4];
  const float* wk  = (const float*)d_in[5];
  const float* wv  = (const float*)d_in[6];
  const float* wg  = (const float*)d_in[7];
  const float* bg  = (const float*)d_in[8];
  const float* wo  = (const float*)d_in[9];
  const float* bo  = (const float*)d_in[10];
  unsigned short* wt = (unsigned short*)d_ws;   // 12288 bf16 = 24 KB scratch
  float* out = (float*)d_out;

  prep_weights<<<dim3(16), dim3(256), 0, stream>>>(wg, wo, wv, wt);
  fused<<<dim3(NB * NL), dim3(512), 0, stream>>>(
      m, msk, lnw, lnb, wq, wk, wt, bg, bo, out);
}